// Round 9
// baseline (64.707 us; speedup 1.0000x reference)
//
#include <hip/hip_runtime.h>

#define TIMESTEPS 1000
#define BATCH 64
#define HH 256
#define WW 256
#define ROWS_PER_WAVE 4
#define WAVES_PER_BLOCK 4
#define NROWS (BATCH * HH)                                   // 16384
#define NBLOCKS (NROWS / (ROWS_PER_WAVE * WAVES_PER_BLOCK))  // 1024
#define NPART (NBLOCKS * WAVES_PER_BLOCK)                    // 4096 per-wave partials
#define HBINS 1024                                           // bins padded 1000 -> 1024
#define NGROUPS 16
#define BLOCKS_PER_GROUP (NBLOCKS / NGROUPS)                 // 64

// d_ws layout (u32 indices):
//   [0, 4096)            per-wave partials
//   GC(i) = 4096 + i*32  group counters, one per 128B line (i = 0..15)
//   MASTER = 4096+512    master counter
#define CTR_BASE 4096
#define MASTER (CTR_BASE + NGROUPS * 32)
#define CTR_ZERO_BYTES ((NGROUPS * 32 + 32) * 4)             // 2176 B

typedef short s16x2 __attribute__((ext_vector_type(2)));

// Round-7 core (best measured 12.76us: float4 loads + LDS atomicMax scatter +
// packed-i16/sdot2 scan) fused with a device-side final reduction:
// two-level completion counters (16 groups of 64 -> master of 16) keep
// same-address atomic bursts at ~64x12ns in parallel lines (round-1 lesson:
// one shared counter for 1024 blocks would cost ~12us). The last block
// re-reads all partials with AGENT-scope loads (bypass local XCD L2 - the
// first timed replay sees 0xAA-poisoned lines that may be cached stale) and
// writes the final mean. Partials are RELEASE-published at agent scope.
__global__ __launch_bounds__(256) void holo_mse_kernel(
    const float* __restrict__ rec, const float* __restrict__ tgt,
    unsigned int* __restrict__ ws, float* __restrict__ out)
{
    __shared__ __align__(16) unsigned int hist[WAVES_PER_BLOCK][2][HBINS]; // 32 KB

    const int tid  = threadIdx.x;
    const int wave = tid >> 6;
    const int lane = tid & 63;

    unsigned int* hr = &hist[wave][0][0];
    unsigned int* ht = &hist[wave][1][0];

    // one-time init (gen 0 == invalid); contiguous b128 writes, uniform banks
    const uint4 z4 = make_uint4(0u, 0u, 0u, 0u);
    #pragma unroll
    for (int k = 0; k < 4; ++k) {
        *(uint4*)&hr[k * 256 + lane * 4] = z4;
        *(uint4*)&ht[k * 256 + lane * 4] = z4;
    }
    __builtin_amdgcn_wave_barrier();

    const int row0 = blockIdx.x * (ROWS_PER_WAVE * WAVES_PER_BLOCK) + wave * ROWS_PER_WAVE;

    unsigned int acc = 0;

    #pragma unroll
    for (int r = 0; r < ROWS_PER_WAVE; ++r) {
        const int row = row0 + r;
        const unsigned int genHi = (unsigned int)(r + 1) << 8;   // 1..4

        const float4 vr4 = *(const float4*)&rec[(size_t)row * WW + lane * 4];
        const float4 vt4 = *(const float4*)&tgt[(size_t)row * WW + lane * 4];
        const float vr[4] = {vr4.x, vr4.y, vr4.z, vr4.w};
        const float vt[4] = {vt4.x, vt4.y, vt4.z, vt4.w};

        // branchless scatter: invalid -> dummy bin 1023 with tag 0 (loses to
        // everything, decodes to 0). Valid t <= 999 so bin 1023 is never a
        // real target. Removes the exec-mask dance around each ds_max.
        #pragma unroll
        for (int j = 0; j < 4; ++j) {
            const unsigned int y = (unsigned int)(lane * 4 + j);
            {
                int t = (int)(vr[j] * 1000.0f) - 1;   // trunc == astype(int32)
                if (t < 0) t += TIMESTEPS;            // python wrap: -1 -> 999
                const bool ok = (vr[j] != 0.0f) & ((unsigned)t < TIMESTEPS);
                atomicMax(&hr[ok ? t : (HBINS - 1)], ok ? (genHi | y) : 0u);
            }
            {
                int t = (int)(vt[j] * 1000.0f) - 1;
                if (t < 0) t += TIMESTEPS;
                const bool ok = (vt[j] != 0.0f) & ((unsigned)t < TIMESTEPS);
                atomicMax(&ht[ok ? t : (HBINS - 1)], ok ? (genHi | y) : 0u);
            }
        }
        __builtin_amdgcn_wave_barrier();   // reads stay after this row's atomics
        // (DS ops within a wave complete in order; barrier is compiler-only)

        // scan: contiguous b128 reads; packed-i16 decode + sdot2 accumulate
        const unsigned int genPk = genHi | (genHi << 16);
        #pragma unroll
        for (int k = 0; k < 4; ++k) {
            const uint4 A = *(const uint4*)&hr[k * 256 + lane * 4];
            const uint4 B = *(const uint4*)&ht[k * 256 + lane * 4];
            const unsigned int Aw[4] = {A.x, A.y, A.z, A.w};
            const unsigned int Bw[4] = {B.x, B.y, B.z, B.w};
            #pragma unroll
            for (int h = 0; h < 2; ++h) {
                unsigned int pa = __builtin_amdgcn_perm(Aw[2*h+1], Aw[2*h], 0x05040100u);
                unsigned int pb = __builtin_amdgcn_perm(Bw[2*h+1], Bw[2*h], 0x05040100u);
                s16x2 ya = (s16x2)(pa) - (s16x2)(genPk);
                s16x2 yb = (s16x2)(pb) - (s16x2)(genPk);
                ya = __builtin_elementwise_max(ya, (s16x2)0);  // stale/empty -> 0
                yb = __builtin_elementwise_max(yb, (s16x2)0);
                const s16x2 d = ya - yb;
#if __has_builtin(__builtin_amdgcn_sdot2)
                acc = (unsigned int)__builtin_amdgcn_sdot2(d, d, (int)acc, false);
#else
                acc += (unsigned int)((int)d.x * (int)d.x + (int)d.y * (int)d.y);
#endif
            }
        }
        __builtin_amdgcn_wave_barrier();   // next row's atomics stay below reads
    }

    // wave reduce -> publish per-wave partial at agent scope (release)
    #pragma unroll
    for (int off = 32; off > 0; off >>= 1) acc += __shfl_down(acc, off, 64);
    if (lane == 0)
        __hip_atomic_store(&ws[blockIdx.x * WAVES_PER_BLOCK + wave], acc,
                           __ATOMIC_RELEASE, __HIP_MEMORY_SCOPE_AGENT);

    __syncthreads();   // compiler emits vmcnt(0) drain: all 4 publishes done

    // two-level completion count; exactly one block sees master == 15
    __shared__ int amLast;
    if (tid == 0) {
        amLast = 0;
        __threadfence();
        const unsigned g = atomicAdd(&ws[CTR_BASE + (blockIdx.x >> 6) * 32], 1u);
        if (g == BLOCKS_PER_GROUP - 1) {
            const unsigned m = atomicAdd(&ws[MASTER], 1u);
            if (m == NGROUPS - 1) amLast = 1;
        }
    }
    __syncthreads();
    if (!amLast) return;

    // last block: every partial is release-published. Agent-scope loads
    // bypass this XCD's L2 (avoids stale poison lines on first timed replay).
    __threadfence();
    unsigned long long s = 0;
    #pragma unroll
    for (int k = 0; k < NPART / 256; ++k) {              // 16 coalesced loads
        s += (unsigned long long)__hip_atomic_load(
                 &ws[k * 256 + tid], __ATOMIC_RELAXED, __HIP_MEMORY_SCOPE_AGENT);
    }
    #pragma unroll
    for (int off = 32; off > 0; off >>= 1) s += __shfl_down(s, off, 64);

    __shared__ unsigned long long wsum[WAVES_PER_BLOCK];
    if (lane == 0) wsum[wave] = s;
    __syncthreads();
    if (tid == 0) {
        const unsigned long long tot = wsum[0] + wsum[1] + wsum[2] + wsum[3];
        const double denom = (double)BATCH * (double)HH * (double)TIMESTEPS; // 16,384,000
        out[0] = (float)((double)tot / denom);
    }
}

extern "C" void kernel_launch(void* const* d_in, const int* in_sizes, int n_in,
                              void* d_out, int out_size, void* d_ws, size_t ws_size,
                              hipStream_t stream) {
    const float* rec = (const float*)d_in[0];
    const float* tgt = (const float*)d_in[1];
    float* out = (float*)d_out;
    unsigned int* ws = (unsigned int*)d_ws;

    // zero ONLY the counter lines each call (graph-capturable, proven round 1)
    hipMemsetAsync((char*)d_ws + CTR_BASE * 4, 0, CTR_ZERO_BYTES, stream);

    holo_mse_kernel<<<NBLOCKS, 256, 0, stream>>>(rec, tgt, ws, out);
}

// Round 10
// 13.256 us; speedup vs baseline: 4.8812x; 4.8812x over previous
//
#include <hip/hip_runtime.h>

#define TIMESTEPS 1000
#define BATCH 64
#define HH 256
#define WW 256
#define ROWS_PER_WAVE 4
#define WAVES_PER_BLOCK 4
#define NROWS (BATCH * HH)                                   // 16384
#define NBLOCKS (NROWS / (ROWS_PER_WAVE * WAVES_PER_BLOCK))  // 1024
#define HBINS 1024                                           // bins padded 1000 -> 1024

typedef short s16x2 __attribute__((ext_vector_type(2)));

// ROUND-7 OPTIMUM, reverted to after three measured dead ends:
//  - r5/r6: 20 and 32 waves/CU both regressed -> DS pipe saturated at 16 w/CU
//  - r8: plain-write scatter (monotone-y) regressed -> scalar-load VMEM blowup
//  - r9: single-kernel fusion regressed 5x -> agent/device fences = L2
//    writeback-invalidate on multi-XCD CDNA4; cross-XCD publication is
//    structurally expensive. Two-kernel structure is the right shape.
// Core: wave-private 1024-bin histograms, gen tags (no re-init), LDS
// atomicMax scatter (last-write-wins == max-y), packed-i16 + sdot2 scan,
// per-block u32 partials, tiny second kernel for the exact u64 sum.
__global__ __launch_bounds__(256) void holo_mse_kernel(
    const float* __restrict__ rec, const float* __restrict__ tgt,
    unsigned int* __restrict__ partials)
{
    __shared__ __align__(16) unsigned int hist[WAVES_PER_BLOCK][2][HBINS]; // 32 KB

    const int tid  = threadIdx.x;
    const int wave = tid >> 6;
    const int lane = tid & 63;

    unsigned int* hr = &hist[wave][0][0];
    unsigned int* ht = &hist[wave][1][0];

    // one-time init (gen 0 == invalid); contiguous b128 writes, uniform banks
    const uint4 z4 = make_uint4(0u, 0u, 0u, 0u);
    #pragma unroll
    for (int k = 0; k < 4; ++k) {
        *(uint4*)&hr[k * 256 + lane * 4] = z4;
        *(uint4*)&ht[k * 256 + lane * 4] = z4;
    }
    __builtin_amdgcn_wave_barrier();

    const int row0 = blockIdx.x * (ROWS_PER_WAVE * WAVES_PER_BLOCK) + wave * ROWS_PER_WAVE;

    unsigned int acc = 0;

    #pragma unroll
    for (int r = 0; r < ROWS_PER_WAVE; ++r) {
        const int row = row0 + r;
        const unsigned int genHi = (unsigned int)(r + 1) << 8;   // 1..4

        const float4 vr4 = *(const float4*)&rec[(size_t)row * WW + lane * 4];
        const float4 vt4 = *(const float4*)&tgt[(size_t)row * WW + lane * 4];
        const float vr[4] = {vr4.x, vr4.y, vr4.z, vr4.w};
        const float vt[4] = {vt4.x, vt4.y, vt4.z, vt4.w};

        #pragma unroll
        for (int j = 0; j < 4; ++j) {
            const unsigned int y = (unsigned int)(lane * 4 + j);
            if (vr[j] != 0.0f) {
                int t = (int)(vr[j] * 1000.0f) - 1;   // trunc == astype(int32)
                if (t < 0) t += TIMESTEPS;            // python wrap: -1 -> 999
                if ((unsigned)t < TIMESTEPS) atomicMax(&hr[t], genHi | y);
            }
            if (vt[j] != 0.0f) {
                int t = (int)(vt[j] * 1000.0f) - 1;
                if (t < 0) t += TIMESTEPS;
                if ((unsigned)t < TIMESTEPS) atomicMax(&ht[t], genHi | y);
            }
        }
        __builtin_amdgcn_wave_barrier();   // reads stay after this row's atomics
        // (DS ops within a wave complete in order; barrier is compiler-only)

        // scan: contiguous b128 reads; packed-i16 decode + sdot2 accumulate
        const unsigned int genPk = genHi | (genHi << 16);
        #pragma unroll
        for (int k = 0; k < 4; ++k) {
            const uint4 A = *(const uint4*)&hr[k * 256 + lane * 4];
            const uint4 B = *(const uint4*)&ht[k * 256 + lane * 4];
            const unsigned int Aw[4] = {A.x, A.y, A.z, A.w};
            const unsigned int Bw[4] = {B.x, B.y, B.z, B.w};
            #pragma unroll
            for (int h = 0; h < 2; ++h) {
                unsigned int pa = __builtin_amdgcn_perm(Aw[2*h+1], Aw[2*h], 0x05040100u);
                unsigned int pb = __builtin_amdgcn_perm(Bw[2*h+1], Bw[2*h], 0x05040100u);
                s16x2 ya = (s16x2)(pa) - (s16x2)(genPk);
                s16x2 yb = (s16x2)(pb) - (s16x2)(genPk);
                ya = __builtin_elementwise_max(ya, (s16x2)0);  // stale/empty -> 0
                yb = __builtin_elementwise_max(yb, (s16x2)0);
                const s16x2 d = ya - yb;
#if __has_builtin(__builtin_amdgcn_sdot2)
                acc = (unsigned int)__builtin_amdgcn_sdot2(d, d, (int)acc, false);
#else
                acc += (unsigned int)((int)d.x * (int)d.x + (int)d.y * (int)d.y);
#endif
            }
        }
        __builtin_amdgcn_wave_barrier();   // next row's atomics stay below reads
    }

    // wave reduce, then one partial per BLOCK (block sum <= 1.05e9, fits u32)
    #pragma unroll
    for (int off = 32; off > 0; off >>= 1) acc += __shfl_down(acc, off, 64);

    __shared__ unsigned int wsum[WAVES_PER_BLOCK];
    if (lane == 0) wsum[wave] = acc;
    __syncthreads();
    if (tid == 0)
        partials[blockIdx.x] = wsum[0] + wsum[1] + wsum[2] + wsum[3];
}

// Single block sums 1024 u32 partials exactly in u64 (4 KB read).
__global__ __launch_bounds__(256) void reduce_kernel(
    const unsigned int* __restrict__ partials, float* __restrict__ out)
{
    const int tid = threadIdx.x;
    const uint4 p = ((const uint4*)partials)[tid];          // 256 * 16B = 4 KB
    unsigned long long s = (unsigned long long)p.x + p.y + p.z + p.w;

    #pragma unroll
    for (int off = 32; off > 0; off >>= 1) s += __shfl_down(s, off, 64);

    __shared__ unsigned long long wsum[4];
    const int wave = tid >> 6;
    if ((tid & 63) == 0) wsum[wave] = s;
    __syncthreads();

    if (tid == 0) {
        unsigned long long tot = wsum[0] + wsum[1] + wsum[2] + wsum[3];
        const double denom = (double)BATCH * (double)HH * (double)TIMESTEPS; // 16,384,000
        out[0] = (float)((double)tot / denom);
    }
}

extern "C" void kernel_launch(void* const* d_in, const int* in_sizes, int n_in,
                              void* d_out, int out_size, void* d_ws, size_t ws_size,
                              hipStream_t stream) {
    const float* rec = (const float*)d_in[0];
    const float* tgt = (const float*)d_in[1];
    float* out = (float*)d_out;
    unsigned int* partials = (unsigned int*)d_ws;   // 1024 * 4 B = 4 KB scratch

    holo_mse_kernel<<<NBLOCKS, 256, 0, stream>>>(rec, tgt, partials);
    reduce_kernel<<<1, 256, 0, stream>>>(partials, out);
}